// Round 15
// baseline (589.835 us; speedup 1.0000x reference)
//
#include <hip/hip_runtime.h>

typedef short bf16x8 __attribute__((ext_vector_type(8)));
typedef float f32x4 __attribute__((ext_vector_type(4)));
typedef int   int4v  __attribute__((ext_vector_type(4)));

#define MFMA16(a, b, c) __builtin_amdgcn_mfma_f32_16x16x32_bf16((a), (b), (c), 0, 0, 0)

static constexpr int T_LEN = 512;
static constexpr int F_DIM = 64;
static constexpr int RPB   = 4;    // batch rows per 64-thread block -> 1024 blocks -> 4/CU
static constexpr float C1  = 2.885390081777927f;  // 2*log2(e)

// exact RNE (one-time weight conversion only)
__device__ __forceinline__ unsigned short brne(float f) {
  unsigned u = __float_as_uint(f);
  return (unsigned short)((u + 0x7fffu + ((u >> 16) & 1u)) >> 16);
}

// round-half-up fp32->bf16 (validated rounds 4-14)
__device__ __forceinline__ unsigned short rhu(float f) {
  return (unsigned short)((__float_as_uint(f) + 0x8000u) >> 16);
}

// v_cvt_pk_bf16_f32: packs 2 fp32 -> 2 bf16 (RNE) in one dword. No builtin.
__device__ __forceinline__ int cvtpk(float lo, float hi) {
  int r;
  asm("v_cvt_pk_bf16_f32 %0, %1, %2" : "=v"(r) : "v"(lo), "v"(hi));
  return r;
}

__device__ __forceinline__ bf16x8 cvt8(const float4 &a, const float4 &b) {
  int4v d = {cvtpk(a.x, a.y), cvtpk(a.z, a.w), cvtpk(b.x, b.y), cvtpk(b.z, b.w)};
  union { int4v i; bf16x8 h; } u;
  u.i = d;
  return u.h;
}

// tanh(s + bias) with bias pre-folded: c2 = C1*bias
__device__ __forceinline__ float tanh_fold(float s, float c2) {
  float e  = __builtin_amdgcn_exp2f(__builtin_fmaf(s, C1, c2));
  float rc = __builtin_amdgcn_rcpf(e + 1.0f);
  return __builtin_fmaf(-2.0f, rc, 1.0f);
}

// One cell, wave-autonomous.  A-rows = 4 batch rows duplicated x4 (row&3), so
// C reg q = batch row q at col 16*ct+(lane&15) for every lane.  Lane l owns
// tile ct=l>>4 in the epilogue => lane l tanh's rows 0-3 of column l.  The
// dep-state is read from rbuf ([4][72] row-major bf16, written last cell by
// THIS wave — same-wave DS-pipe ordering, no barrier).  Dep frags returned
// in d0/d1 (they are the next cell's own-state carry).  Tile-select for the
// epilogue is a static-indexed cndmask tree (no runtime array indexing).
template<bool FIN>
__device__ __forceinline__ void cell(
    const bf16x8 &x0, const bf16x8 &x1,
    const bf16x8 &o0, const bf16x8 &o1,      // own old state (carried in regs)
    bf16x8 &d0, bf16x8 &d1,                  // OUT: dep-state frags read here
    const bf16x8 (&W)[4][6],
    unsigned short (*rbuf)[72], unsigned short (*wbuf)[72],
    float (*fin)[64], float c2,
    int br, int g8, int G, int lane, const f32x4 &Z)
{
  // dep-state A-frags: row br, cols [g8,g8+8) and [32+g8,..) — aligned b128s
  d0 = *(const bf16x8 *)&rbuf[br][g8];
  d1 = *(const bf16x8 *)&rbuf[br][32 + g8];
  // 4 independent 6-deep chains; dep-frag MFMAs last (read-latency tail = 2)
  f32x4 a0 = MFMA16(x0, W[0][0], Z);
  f32x4 a1 = MFMA16(x0, W[1][0], Z);
  f32x4 a2 = MFMA16(x0, W[2][0], Z);
  f32x4 a3 = MFMA16(x0, W[3][0], Z);
  a0 = MFMA16(x1, W[0][1], a0);
  a1 = MFMA16(x1, W[1][1], a1);
  a2 = MFMA16(x1, W[2][1], a2);
  a3 = MFMA16(x1, W[3][1], a3);
  a0 = MFMA16(o0, W[0][4], a0);
  a1 = MFMA16(o0, W[1][4], a1);
  a2 = MFMA16(o0, W[2][4], a2);
  a3 = MFMA16(o0, W[3][4], a3);
  a0 = MFMA16(o1, W[0][5], a0);
  a1 = MFMA16(o1, W[1][5], a1);
  a2 = MFMA16(o1, W[2][5], a2);
  a3 = MFMA16(o1, W[3][5], a3);
  a0 = MFMA16(d0, W[0][2], a0);
  a1 = MFMA16(d0, W[1][2], a1);
  a2 = MFMA16(d0, W[2][2], a2);
  a3 = MFMA16(d0, W[3][2], a3);
  a0 = MFMA16(d1, W[0][3], a0);
  a1 = MFMA16(d1, W[1][3], a1);
  a2 = MFMA16(d1, W[2][3], a2);
  a3 = MFMA16(d1, W[3][3], a3);
  // epilogue: lane handles rows 0-3 of col=lane from tile G=lane>>4
#pragma unroll
  for (int q = 0; q < 4; ++q) {
    float s01 = (G & 1) ? a1[q] : a0[q];
    float s23 = (G & 1) ? a3[q] : a2[q];
    float z   = (G & 2) ? s23 : s01;
    float tv  = tanh_fold(z, c2);
    wbuf[q][lane] = rhu(tv);
    if (FIN) fin[q][lane] = tv;
  }
}

__global__ __launch_bounds__(64, 1)
void mr_rnn_kernel(const float *__restrict__ x,
                   const float *__restrict__ mWih, const float *__restrict__ mWhh,
                   const float *__restrict__ mbih, const float *__restrict__ mbhh,
                   const float *__restrict__ pWih, const float *__restrict__ pWhh,
                   const float *__restrict__ pbih, const float *__restrict__ pbhh,
                   const float *__restrict__ plW,  const float *__restrict__ plb,
                   const float *__restrict__ mlW,  const float *__restrict__ mlb,
                   float *__restrict__ out, int B)
{
  // per-wave private buffers; NO __syncthreads anywhere in the time loop
  __shared__ __align__(16) unsigned short mT[RPB][72], pT[RPB][72];
  __shared__ __align__(16) float s_mfin[RPB][64], s_pfin[RPB][64];

  const int lane = threadIdx.x;     // 0..63, single wave
  const int l15  = lane & 15;
  const int br   = lane & 3;        // A-frag batch row (x4 duplicated rows)
  const int G    = lane >> 4;       // k-subgroup AND owned epilogue tile
  const int g8   = G * 8;
  const int b0   = blockIdx.x * RPB;

  // ---- register-resident weights for ALL 4 col-tiles: B[ct][kt]
  bf16x8 Bm[4][6], Bp[4][6];
#pragma unroll
  for (int ct = 0; ct < 4; ++ct) {
    const int j = ct * 16 + l15;
#pragma unroll
    for (int kt = 0; kt < 6; ++kt) {
      const int k0 = kt * 32 + g8;
#pragma unroll
      for (int i = 0; i < 8; ++i) {
        const int k = k0 + i;
        float wm = (k < 128) ? mWih[j * 128 + k] : mWhh[j * 64 + (k - 128)];
        float wp = (k < 128) ? pWih[j * 128 + k] : pWhh[j * 64 + (k - 128)];
        Bm[ct][kt][i] = (short)brne(wm);
        Bp[ct][kt][i] = (short)brne(wp);
      }
    }
  }
  // epilogue bias for owned column (= lane)
  const float c2m = C1 * (mbih[lane] + mbhh[lane]);
  const float c2p = C1 * (pbih[lane] + pbhh[lane]);
  const f32x4 Z = {0.f, 0.f, 0.f, 0.f};

  // ---- init: p(-1) = 0 in pT (same-wave DS order; no barrier); m(-1)=0 regs
#pragma unroll
  for (int q = 0; q < RPB; ++q) pT[q][lane] = 0;
  bf16x8 mo0 = {0, 0, 0, 0, 0, 0, 0, 0};
  bf16x8 mo1 = {0, 0, 0, 0, 0, 0, 0, 0};
  bf16x8 po0, po1;

  // ---- x stream: lane covers batch b0+br, cols [g8,g8+8) & [32+g8,..),
  //      every step; 2-deep named-register prefetch (Q/R).
  const float *pxl = x + (size_t)(b0 + br) * T_LEN * F_DIM + g8;
  float4 Q0 = *(const float4 *)(pxl);
  float4 Q1 = *(const float4 *)(pxl + 4);
  float4 Q2 = *(const float4 *)(pxl + 32);
  float4 Q3 = *(const float4 *)(pxl + 36);
  bf16x8 x0 = cvt8(Q0, Q1);
  bf16x8 x1 = cvt8(Q2, Q3);
  float4 R0 = *(const float4 *)(pxl + F_DIM);
  float4 R1 = *(const float4 *)(pxl + F_DIM + 4);
  float4 R2 = *(const float4 *)(pxl + F_DIM + 32);
  float4 R3 = *(const float4 *)(pxl + F_DIM + 36);

  // invariant at loop top: x0/x1 = x(t), R = raw x(t+1)
#pragma unroll 1
  for (int t = 0; t < T_LEN - 2; t += 2) {
    Q0 = *(const float4 *)(pxl + 2 * F_DIM);
    Q1 = *(const float4 *)(pxl + 2 * F_DIM + 4);
    Q2 = *(const float4 *)(pxl + 2 * F_DIM + 32);
    Q3 = *(const float4 *)(pxl + 2 * F_DIM + 36);
    // step t: m-cell (dep p(t-1) from pT -> po), p-cell (dep m(t) -> mo)
    cell<false>(x0, x1, mo0, mo1, po0, po1, Bm, pT, mT, s_mfin, c2m,
                br, g8, G, lane, Z);
    cell<false>(x0, x1, po0, po1, mo0, mo1, Bp, mT, pT, s_pfin, c2p,
                br, g8, G, lane, Z);
    x0 = cvt8(R0, R1);
    x1 = cvt8(R2, R3);
    R0 = *(const float4 *)(pxl + 3 * F_DIM);
    R1 = *(const float4 *)(pxl + 3 * F_DIM + 4);
    R2 = *(const float4 *)(pxl + 3 * F_DIM + 32);
    R3 = *(const float4 *)(pxl + 3 * F_DIM + 36);
    // step t+1
    cell<false>(x0, x1, mo0, mo1, po0, po1, Bm, pT, mT, s_mfin, c2m,
                br, g8, G, lane, Z);
    cell<false>(x0, x1, po0, po1, mo0, mo1, Bp, mT, pT, s_pfin, c2p,
                br, g8, G, lane, Z);
    x0 = cvt8(Q0, Q1);
    x1 = cvt8(Q2, Q3);
    pxl += 2 * F_DIM;
  }
  // ---- tail: steps 510, 511 (511 writes fp32 finals)
  cell<false>(x0, x1, mo0, mo1, po0, po1, Bm, pT, mT, s_mfin, c2m,
              br, g8, G, lane, Z);
  cell<false>(x0, x1, po0, po1, mo0, mo1, Bp, mT, pT, s_pfin, c2p,
              br, g8, G, lane, Z);
  x0 = cvt8(R0, R1);
  x1 = cvt8(R2, R3);
  cell<true>(x0, x1, mo0, mo1, po0, po1, Bm, pT, mT, s_mfin, c2m,
             br, g8, G, lane, Z);
  cell<true>(x0, x1, po0, po1, mo0, mo1, Bp, mT, pT, s_pfin, c2p,
             br, g8, G, lane, Z);

  // ---- heads (same wave wrote the fins; compiler orders via lgkmcnt)
  if (lane < RPB) {
    const int b = lane;
    float acc = plb[0];
#pragma unroll 1
    for (int k = 0; k < 64; ++k) acc += s_pfin[b][k] * plW[k];
    out[b0 + b] = acc;
  } else if (lane < RPB + RPB * 8) {
    const int r = lane - RPB;
    const int b = r >> 3, e = r & 7;
    float acc = mlb[e];
#pragma unroll 1
    for (int k = 0; k < 64; ++k) acc += s_mfin[b][k] * mlW[e * 64 + k];
    out[(size_t)B + (size_t)(b0 + b) * 8 + e] = acc;
  }
}

extern "C" void kernel_launch(void* const* d_in, const int* in_sizes, int n_in,
                              void* d_out, int out_size, void* d_ws, size_t ws_size,
                              hipStream_t stream) {
  (void)n_in; (void)out_size; (void)d_ws; (void)ws_size;
  const float* x    = (const float*)d_in[0];
  const float* mWih = (const float*)d_in[1];
  const float* mWhh = (const float*)d_in[2];
  const float* mbih = (const float*)d_in[3];
  const float* mbhh = (const float*)d_in[4];
  const float* pWih = (const float*)d_in[5];
  const float* pWhh = (const float*)d_in[6];
  const float* pbih = (const float*)d_in[7];
  const float* pbhh = (const float*)d_in[8];
  const float* plW  = (const float*)d_in[9];
  const float* plb  = (const float*)d_in[10];
  const float* mlW  = (const float*)d_in[11];
  const float* mlb  = (const float*)d_in[12];
  const int B = in_sizes[0] / (T_LEN * F_DIM);
  const int nblk = B / RPB;   // 1024 single-wave blocks -> 4/CU, barrier-free
  mr_rnn_kernel<<<dim3(nblk), dim3(64), 0, stream>>>(
      x, mWih, mWhh, mbih, mbhh, pWih, pWhh, pbih, pbhh,
      plW, plb, mlW, mlb, (float*)d_out, B);
}

// Round 16
// 329.274 us; speedup vs baseline: 1.7913x; 1.7913x over previous
//
#include <hip/hip_runtime.h>

typedef short bf16x8 __attribute__((ext_vector_type(8)));
typedef float f32x4 __attribute__((ext_vector_type(4)));
typedef int   int4v  __attribute__((ext_vector_type(4)));

#define MFMA16(a, b, c) __builtin_amdgcn_mfma_f32_16x16x32_bf16((a), (b), (c), 0, 0, 0)

static constexpr int T_LEN = 512;
static constexpr int F_DIM = 64;
static constexpr int NB    = 16;   // batch rows per block -> 256 blocks -> 1 block/CU
static constexpr float C1  = 2.885390081777927f;  // 2*log2(e)

// exact RNE (one-time weight conversion only)
__device__ __forceinline__ unsigned short brne(float f) {
  unsigned u = __float_as_uint(f);
  return (unsigned short)((u + 0x7fffu + ((u >> 16) & 1u)) >> 16);
}

// v_cvt_pk_bf16_f32: packs 2 fp32 -> 2 bf16 (RNE) in one dword. No builtin.
__device__ __forceinline__ int cvtpk(float lo, float hi) {
  int r;
  asm("v_cvt_pk_bf16_f32 %0, %1, %2" : "=v"(r) : "v"(lo), "v"(hi));
  return r;
}

__device__ __forceinline__ bf16x8 cvt8(const float4 &a, const float4 &b) {
  int4v d = {cvtpk(a.x, a.y), cvtpk(a.z, a.w), cvtpk(b.x, b.y), cvtpk(b.z, b.w)};
  union { int4v i; bf16x8 h; } u;
  u.i = d;
  return u.h;
}

// DPP quad_perm(1,0,3,2): fetch xor-1 lane neighbor (all lanes active)
__device__ __forceinline__ float xor1(float v) {
  return __int_as_float(__builtin_amdgcn_mov_dpp(__float_as_int(v), 0xB1, 0xF, 0xF, true));
}

// tanh(s + bias) with bias pre-folded: c2 = C1*bias
__device__ __forceinline__ float tanh_fold(float s, float c2) {
  float e  = __builtin_amdgcn_exp2f(__builtin_fmaf(s, C1, c2));
  float rc = __builtin_amdgcn_rcpf(e + 1.0f);
  return __builtin_fmaf(-2.0f, rc, 1.0f);
}

// Raw workgroup barrier: orders LDS writes (lgkmcnt) but leaves global x
// prefetch loads (vmcnt) in flight.  sched_barrier(0) is mandatory: LLVM's
// s_barrier is NOT a memory fence and will hoist post-barrier ds_reads
// (round-9 NaN lesson).  Validated rounds 8, 13, 14.
__device__ __forceinline__ void bar() {
  asm volatile("s_waitcnt lgkmcnt(0)" ::: "memory");
  __builtin_amdgcn_s_barrier();
  __builtin_amdgcn_sched_barrier(0);
}

// One RNN step (m-cell then p-cell).  NB=16: zero MFMA row-duplication; lane
// owns C rows 4g..4g+3 at col j.  m_old carried in registers (round-12).
// PACKED STATE WRITES (round-6-validated pattern): odd-lane tanh fetched via
// DPP xor1, packed with cvtpk (RNE), even lanes write 4 b32 — halves LDS
// write ops and the pre-barrier lgkmcnt drain.
template<bool FIN>
__device__ __forceinline__ void step_cells(
    int arow, int g8, int j, bool evn, int rowb,
    const bf16x8 &x0, const bf16x8 &x1,
    bf16x8 &mo0, bf16x8 &mo1,
    const bf16x8 (&Bm)[6], const bf16x8 (&Bp)[6],
    float c2m, float c2p, const f32x4 &Z,
    unsigned short (*sm)[72],
    unsigned short (*sp_c)[72], unsigned short (*sp_p)[72],
    float (*mfin)[68], float (*pfin)[68])
{
  // p_old fragments (used by both cells; buffer not rewritten this step)
  bf16x8 p0 = *(const bf16x8 *)&sp_p[arow][g8];
  bf16x8 p1 = *(const bf16x8 *)&sp_p[arow][32 + g8];

  // ---------------- metrics cell: in = [x | p_old | m_old(carried)]
  {
    f32x4 a0 = MFMA16(x0, Bm[0], Z);
    f32x4 a1 = MFMA16(x1, Bm[1], Z);
    a0 = MFMA16(p0, Bm[2], a0);
    a1 = MFMA16(p1, Bm[3], a1);
    a0 = MFMA16(mo0, Bm[4], a0);
    a1 = MFMA16(mo1, Bm[5], a1);
#pragma unroll
    for (int r = 0; r < 4; ++r) {
      float tv = tanh_fold(a0[r] + a1[r], c2m);
      float nv = xor1(tv);                       // col j^1's value
      if (evn) *(unsigned *)&sm[rowb + r][j] = (unsigned)cvtpk(tv, nv);
      if (FIN) mfin[rowb + r][j] = tv;
    }
  }
  bar();   // m_new visible to all waves
  // ---------------- price cell: in = [x | m_new | p_old]
  {
    bf16x8 n0 = *(const bf16x8 *)&sm[arow][g8];
    bf16x8 n1 = *(const bf16x8 *)&sm[arow][32 + g8];
    f32x4 b0 = MFMA16(x0, Bp[0], Z);
    f32x4 b1 = MFMA16(x1, Bp[1], Z);
    b0 = MFMA16(n0, Bp[2], b0);
    b1 = MFMA16(n1, Bp[3], b1);
    b0 = MFMA16(p0, Bp[4], b0);
    b1 = MFMA16(p1, Bp[5], b1);
#pragma unroll
    for (int r = 0; r < 4; ++r) {
      float tv = tanh_fold(b0[r] + b1[r], c2p);
      float nv = xor1(tv);
      if (evn) *(unsigned *)&sp_c[rowb + r][j] = (unsigned)cvtpk(tv, nv);
      if (FIN) pfin[rowb + r][j] = tv;
    }
    mo0 = n0;   // carry m(t) -> next step's m_old
    mo1 = n1;
  }
  bar();   // p_new visible; prev p-buffer free next step
}

__global__ __launch_bounds__(256, 1)
void mr_rnn_kernel(const float *__restrict__ x,
                   const float *__restrict__ mWih, const float *__restrict__ mWhh,
                   const float *__restrict__ mbih, const float *__restrict__ mbhh,
                   const float *__restrict__ pWih, const float *__restrict__ pWhh,
                   const float *__restrict__ pbih, const float *__restrict__ pbhh,
                   const float *__restrict__ plW,  const float *__restrict__ plb,
                   const float *__restrict__ mlW,  const float *__restrict__ mlb,
                   float *__restrict__ out, int B)
{
  __shared__ __align__(16) unsigned short sm[NB][72];      // single m buffer
  __shared__ __align__(16) unsigned short sp[2][NB][72];   // p double buffer
  __shared__ __align__(16) float s_mfin[NB][68], s_pfin[NB][68];

  const int tid  = threadIdx.x;
  const int lane = tid & 63;
  const int q    = tid >> 6;        // wave id -> output col tile
  const int l15  = lane & 15;
  const int arow = l15;             // batch row within block (all 16 distinct)
  const int g    = lane >> 4;       // k-group
  const int j    = q * 16 + l15;    // output feature owned by this lane's wave
  const int b0   = blockIdx.x * NB;
  const int g8   = g * 8;
  const int rowb = g * 4;           // C rows 4g..4g+3 owned by this lane
  const bool evn = (l15 & 1) == 0;  // packed-write lane (cols j, j+1)

  // ---- register-resident bf16 weight B-fragments: B[k][j] = W[j][k]
  bf16x8 Bm[6], Bp[6];
#pragma unroll
  for (int kt = 0; kt < 6; ++kt) {
    const int k0 = kt * 32 + g8;
#pragma unroll
    for (int i = 0; i < 8; ++i) {
      const int k = k0 + i;
      float wm = (k < 128) ? mWih[j * 128 + k] : mWhh[j * 64 + (k - 128)];
      float wp = (k < 128) ? pWih[j * 128 + k] : pWhh[j * 64 + (k - 128)];
      Bm[kt][i] = (short)brne(wm);
      Bp[kt][i] = (short)brne(wp);
    }
  }
  const float c2m = C1 * (mbih[j] + mbhh[j]);   // bias folded into exp2 arg
  const float c2p = C1 * (pbih[j] + pbhh[j]);
  const f32x4 Z = {0.f, 0.f, 0.f, 0.f};         // hoisted accumulator seed

  // ---- zero the t=-1 p-state buffer (parity index 1); m(-1)=0 is carried
  for (int idx = tid; idx < NB * 72; idx += 256) {
    const int bb = idx / 72, kk = idx % 72;
    sp[1][bb][kk] = 0;
  }
  bf16x8 mo0 = {0, 0, 0, 0, 0, 0, 0, 0};   // m(-1) = 0 (bf16 zero bits)
  bf16x8 mo1 = {0, 0, 0, 0, 0, 0, 0, 0};

  // ---- x stream: lane covers batch b0+arow, features [g8,g8+8) and
  //      [32+g8,32+g8+8), EVERY step.  2-deep named-register prefetch (Q/R).
  const float *pxl = x + (size_t)(b0 + arow) * T_LEN * F_DIM + g8;
  float4 Q0 = *(const float4 *)(pxl);
  float4 Q1 = *(const float4 *)(pxl + 4);
  float4 Q2 = *(const float4 *)(pxl + 32);
  float4 Q3 = *(const float4 *)(pxl + 36);
  bf16x8 x0 = cvt8(Q0, Q1);
  bf16x8 x1 = cvt8(Q2, Q3);
  float4 R0 = *(const float4 *)(pxl + F_DIM);
  float4 R1 = *(const float4 *)(pxl + F_DIM + 4);
  float4 R2 = *(const float4 *)(pxl + F_DIM + 32);
  float4 R3 = *(const float4 *)(pxl + F_DIM + 36);
  __syncthreads();   // zero-init visible (one full drain, outside the loop)

  // invariant at loop top: x0/x1 = x(t) converted, R = raw x(t+1)
#pragma unroll 1
  for (int t = 0; t < T_LEN - 2; t += 2) {
    // prefetch raw x(t+2) into Q (stays in flight across bar()s)
    Q0 = *(const float4 *)(pxl + 2 * F_DIM);
    Q1 = *(const float4 *)(pxl + 2 * F_DIM + 4);
    Q2 = *(const float4 *)(pxl + 2 * F_DIM + 32);
    Q3 = *(const float4 *)(pxl + 2 * F_DIM + 36);
    // step t (even): p cur parity 0, prev 1
    step_cells<false>(arow, g8, j, evn, rowb, x0, x1, mo0, mo1,
                      Bm, Bp, c2m, c2p, Z,
                      sm, sp[0], sp[1], s_mfin, s_pfin);
    x0 = cvt8(R0, R1);   // x(t+1)
    x1 = cvt8(R2, R3);
    // prefetch raw x(t+3) into R
    R0 = *(const float4 *)(pxl + 3 * F_DIM);
    R1 = *(const float4 *)(pxl + 3 * F_DIM + 4);
    R2 = *(const float4 *)(pxl + 3 * F_DIM + 32);
    R3 = *(const float4 *)(pxl + 3 * F_DIM + 36);
    // step t+1 (odd): p cur parity 1, prev 0
    step_cells<false>(arow, g8, j, evn, rowb, x0, x1, mo0, mo1,
                      Bm, Bp, c2m, c2p, Z,
                      sm, sp[1], sp[0], s_mfin, s_pfin);
    x0 = cvt8(Q0, Q1);   // x(t+2)
    x1 = cvt8(Q2, Q3);
    pxl += 2 * F_DIM;
  }
  // ---- tail: steps 510, 511 (x0=x(510), R=raw x(511); 511 writes finals)
  step_cells<false>(arow, g8, j, evn, rowb, x0, x1, mo0, mo1,
                    Bm, Bp, c2m, c2p, Z,
                    sm, sp[0], sp[1], s_mfin, s_pfin);
  x0 = cvt8(R0, R1);
  x1 = cvt8(R2, R3);
  step_cells<true>(arow, g8, j, evn, rowb, x0, x1, mo0, mo1,
                   Bm, Bp, c2m, c2p, Z,
                   sm, sp[1], sp[0], s_mfin, s_pfin);
  __syncthreads();   // finals visible to head threads (full drain, once)

  // ---- heads
  if (tid < NB) {
    const int b = tid;
    float acc = plb[0];
#pragma unroll 1
    for (int k = 0; k < 64; ++k) acc += s_pfin[b][k] * plW[k];
    out[b0 + b] = acc;
  } else if (tid < NB + NB * 8) {
    const int r = tid - NB;
    const int b = r >> 3, e = r & 7;
    float acc = mlb[e];
#pragma unroll 1
    for (int k = 0; k < 64; ++k) acc += s_mfin[b][k] * mlW[e * 64 + k];
    out[(size_t)B + (size_t)(b0 + b) * 8 + e] = acc;
  }
}

extern "C" void kernel_launch(void* const* d_in, const int* in_sizes, int n_in,
                              void* d_out, int out_size, void* d_ws, size_t ws_size,
                              hipStream_t stream) {
  (void)n_in; (void)out_size; (void)d_ws; (void)ws_size;
  const float* x    = (const float*)d_in[0];
  const float* mWih = (const float*)d_in[1];
  const float* mWhh = (const float*)d_in[2];
  const float* mbih = (const float*)d_in[3];
  const float* mbhh = (const float*)d_in[4];
  const float* pWih = (const float*)d_in[5];
  const float* pWhh = (const float*)d_in[6];
  const float* pbih = (const float*)d_in[7];
  const float* pbhh = (const float*)d_in[8];
  const float* plW  = (const float*)d_in[9];
  const float* plb  = (const float*)d_in[10];
  const float* mlW  = (const float*)d_in[11];
  const float* mlb  = (const float*)d_in[12];
  const int B = in_sizes[0] / (T_LEN * F_DIM);
  const int nblk = B / NB;   // 256 blocks -> 1 block/CU, 16 valid rows/MFMA
  mr_rnn_kernel<<<dim3(nblk), dim3(256), 0, stream>>>(
      x, mWih, mWhh, mbih, mbhh, pWih, pWhh, pbih, pbhh,
      plW, plb, mlW, mlb, (float*)d_out, B);
}

// Round 17
// 264.133 us; speedup vs baseline: 2.2331x; 1.2466x over previous
//
#include <hip/hip_runtime.h>

typedef short bf16x8 __attribute__((ext_vector_type(8)));
typedef float f32x4 __attribute__((ext_vector_type(4)));
typedef int   int4v  __attribute__((ext_vector_type(4)));

#define MFMA16(a, b, c) __builtin_amdgcn_mfma_f32_16x16x32_bf16((a), (b), (c), 0, 0, 0)

static constexpr int T_LEN = 512;
static constexpr int F_DIM = 64;
static constexpr int NB    = 16;   // batch rows per block -> 256 blocks -> 1 block/CU
static constexpr float C1  = 2.885390081777927f;  // 2*log2(e)

// exact RNE (one-time weight conversion only)
__device__ __forceinline__ unsigned short brne(float f) {
  unsigned u = __float_as_uint(f);
  return (unsigned short)((u + 0x7fffu + ((u >> 16) & 1u)) >> 16);
}

// round-half-up fp32->bf16 (2 VALU ops; validated rounds 4-13)
__device__ __forceinline__ unsigned short rhu(float f) {
  return (unsigned short)((__float_as_uint(f) + 0x8000u) >> 16);
}

// v_cvt_pk_bf16_f32: packs 2 fp32 -> 2 bf16 (RNE) in one dword. No builtin.
__device__ __forceinline__ int cvtpk(float lo, float hi) {
  int r;
  asm("v_cvt_pk_bf16_f32 %0, %1, %2" : "=v"(r) : "v"(lo), "v"(hi));
  return r;
}

__device__ __forceinline__ bf16x8 cvt8(const float4 &a, const float4 &b) {
  int4v d = {cvtpk(a.x, a.y), cvtpk(a.z, a.w), cvtpk(b.x, b.y), cvtpk(b.z, b.w)};
  union { int4v i; bf16x8 h; } u;
  u.i = d;
  return u.h;
}

// tanh(s + bias) with bias pre-folded: c2 = C1*bias
__device__ __forceinline__ float tanh_fold(float s, float c2) {
  float e  = __builtin_amdgcn_exp2f(__builtin_fmaf(s, C1, c2));
  float rc = __builtin_amdgcn_rcpf(e + 1.0f);
  return __builtin_fmaf(-2.0f, rc, 1.0f);
}

// Raw workgroup barrier: orders LDS writes (lgkmcnt) but leaves global x
// prefetch loads (vmcnt) in flight.  sched_barrier(0) is mandatory: LLVM's
// s_barrier is NOT a memory fence and will hoist post-barrier ds_reads
// (round-9 NaN lesson).  Validated rounds 8, 13, 14.
__device__ __forceinline__ void bar() {
  asm volatile("s_waitcnt lgkmcnt(0)" ::: "memory");
  __builtin_amdgcn_s_barrier();
  __builtin_amdgcn_sched_barrier(0);
}

// One RNN step (m-cell then p-cell).  NB=16: all 16 A-rows are distinct batch
// rows — zero MFMA duplication, and every C element is valid: lane holds
// rows 4g+r (r=0..3) at col j.  No parity machinery, no redistribution.
// m_old carried in registers (mo = n from the p-cell, validated round 12).
// NOTE (r14/r16): chain-reorder/hoist and packed-write variants were tried
// and were neutral/regressive — this simple form is the measured optimum.
template<bool FIN>
__device__ __forceinline__ void step_cells(
    int arow, int g8, int j, int rowb,
    const bf16x8 &x0, const bf16x8 &x1,
    bf16x8 &mo0, bf16x8 &mo1,
    const bf16x8 (&Bm)[6], const bf16x8 (&Bp)[6],
    float c2m, float c2p, const f32x4 &Z,
    unsigned short (*sm)[72],
    unsigned short (*sp_c)[72], unsigned short (*sp_p)[72],
    float (*mfin)[68], float (*pfin)[68])
{
  // p_old fragments (used by both cells; buffer not rewritten this step)
  bf16x8 p0 = *(const bf16x8 *)&sp_p[arow][g8];
  bf16x8 p1 = *(const bf16x8 *)&sp_p[arow][32 + g8];

  // ---------------- metrics cell: in = [x | p_old | m_old(carried)]
  {
    f32x4 a0 = MFMA16(x0, Bm[0], Z);
    f32x4 a1 = MFMA16(x1, Bm[1], Z);
    a0 = MFMA16(p0, Bm[2], a0);
    a1 = MFMA16(p1, Bm[3], a1);
    a0 = MFMA16(mo0, Bm[4], a0);
    a1 = MFMA16(mo1, Bm[5], a1);
#pragma unroll
    for (int r = 0; r < 4; ++r) {
      float tv = tanh_fold(a0[r] + a1[r], c2m);
      sm[rowb + r][j] = rhu(tv);
      if (FIN) mfin[rowb + r][j] = tv;
    }
  }
  bar();   // m_new visible to all waves
  // ---------------- price cell: in = [x | m_new | p_old]
  {
    bf16x8 n0 = *(const bf16x8 *)&sm[arow][g8];
    bf16x8 n1 = *(const bf16x8 *)&sm[arow][32 + g8];
    f32x4 b0 = MFMA16(x0, Bp[0], Z);
    f32x4 b1 = MFMA16(x1, Bp[1], Z);
    b0 = MFMA16(n0, Bp[2], b0);
    b1 = MFMA16(n1, Bp[3], b1);
    b0 = MFMA16(p0, Bp[4], b0);
    b1 = MFMA16(p1, Bp[5], b1);
#pragma unroll
    for (int r = 0; r < 4; ++r) {
      float tv = tanh_fold(b0[r] + b1[r], c2p);
      sp_c[rowb + r][j] = rhu(tv);
      if (FIN) pfin[rowb + r][j] = tv;
    }
    mo0 = n0;   // carry m(t) -> next step's m_old
    mo1 = n1;
  }
  bar();   // p_new visible; prev p-buffer free next step
}

__global__ __launch_bounds__(256, 1)
void mr_rnn_kernel(const float *__restrict__ x,
                   const float *__restrict__ mWih, const float *__restrict__ mWhh,
                   const float *__restrict__ mbih, const float *__restrict__ mbhh,
                   const float *__restrict__ pWih, const float *__restrict__ pWhh,
                   const float *__restrict__ pbih, const float *__restrict__ pbhh,
                   const float *__restrict__ plW,  const float *__restrict__ plb,
                   const float *__restrict__ mlW,  const float *__restrict__ mlb,
                   float *__restrict__ out, int B)
{
  __shared__ __align__(16) unsigned short sm[NB][72];      // single m buffer
  __shared__ __align__(16) unsigned short sp[2][NB][72];   // p double buffer
  __shared__ __align__(16) float s_mfin[NB][68], s_pfin[NB][68];

  const int tid  = threadIdx.x;
  const int lane = tid & 63;
  const int q    = tid >> 6;        // wave id -> output col tile
  const int l15  = lane & 15;
  const int arow = l15;             // batch row within block (all 16 distinct)
  const int g    = lane >> 4;       // k-group
  const int j    = q * 16 + l15;    // output feature owned by this lane's wave
  const int b0   = blockIdx.x * NB;
  const int g8   = g * 8;
  const int rowb = g * 4;           // C rows 4g..4g+3 owned by this lane

  // ---- register-resident bf16 weight B-fragments: B[k][j] = W[j][k]
  bf16x8 Bm[6], Bp[6];
#pragma unroll
  for (int kt = 0; kt < 6; ++kt) {
    const int k0 = kt * 32 + g8;
#pragma unroll
    for (int i = 0; i < 8; ++i) {
      const int k = k0 + i;
      float wm = (k < 128) ? mWih[j * 128 + k] : mWhh[j * 64 + (k - 128)];
      float wp = (k < 128) ? pWih[j * 128 + k] : pWhh[j * 64 + (k - 128)];
      Bm[kt][i] = (short)brne(wm);
      Bp[kt][i] = (short)brne(wp);
    }
  }
  const float c2m = C1 * (mbih[j] + mbhh[j]);   // bias folded into exp2 arg
  const float c2p = C1 * (pbih[j] + pbhh[j]);
  const f32x4 Z = {0.f, 0.f, 0.f, 0.f};         // hoisted accumulator seed

  // ---- zero the t=-1 p-state buffer (parity index 1); m(-1)=0 is carried
  for (int idx = tid; idx < NB * 72; idx += 256) {
    const int bb = idx / 72, kk = idx % 72;
    sp[1][bb][kk] = 0;
  }
  bf16x8 mo0 = {0, 0, 0, 0, 0, 0, 0, 0};   // m(-1) = 0 (bf16 zero bits)
  bf16x8 mo1 = {0, 0, 0, 0, 0, 0, 0, 0};

  // ---- x stream: lane covers batch b0+arow, features [g8,g8+8) and
  //      [32+g8,32+g8+8), EVERY step.  2-deep named-register prefetch (Q/R).
  const float *pxl = x + (size_t)(b0 + arow) * T_LEN * F_DIM + g8;
  float4 Q0 = *(const float4 *)(pxl);
  float4 Q1 = *(const float4 *)(pxl + 4);
  float4 Q2 = *(const float4 *)(pxl + 32);
  float4 Q3 = *(const float4 *)(pxl + 36);
  bf16x8 x0 = cvt8(Q0, Q1);
  bf16x8 x1 = cvt8(Q2, Q3);
  float4 R0 = *(const float4 *)(pxl + F_DIM);
  float4 R1 = *(const float4 *)(pxl + F_DIM + 4);
  float4 R2 = *(const float4 *)(pxl + F_DIM + 32);
  float4 R3 = *(const float4 *)(pxl + F_DIM + 36);
  __syncthreads();   // zero-init visible (one full drain, outside the loop)

  // invariant at loop top: x0/x1 = x(t) converted, R = raw x(t+1)
#pragma unroll 1
  for (int t = 0; t < T_LEN - 2; t += 2) {
    // prefetch raw x(t+2) into Q (stays in flight across bar()s)
    Q0 = *(const float4 *)(pxl + 2 * F_DIM);
    Q1 = *(const float4 *)(pxl + 2 * F_DIM + 4);
    Q2 = *(const float4 *)(pxl + 2 * F_DIM + 32);
    Q3 = *(const float4 *)(pxl + 2 * F_DIM + 36);
    // step t (even): p cur parity 0, prev 1
    step_cells<false>(arow, g8, j, rowb, x0, x1, mo0, mo1,
                      Bm, Bp, c2m, c2p, Z,
                      sm, sp[0], sp[1], s_mfin, s_pfin);
    x0 = cvt8(R0, R1);   // x(t+1)
    x1 = cvt8(R2, R3);
    // prefetch raw x(t+3) into R
    R0 = *(const float4 *)(pxl + 3 * F_DIM);
    R1 = *(const float4 *)(pxl + 3 * F_DIM + 4);
    R2 = *(const float4 *)(pxl + 3 * F_DIM + 32);
    R3 = *(const float4 *)(pxl + 3 * F_DIM + 36);
    // step t+1 (odd): p cur parity 1, prev 0
    step_cells<false>(arow, g8, j, rowb, x0, x1, mo0, mo1,
                      Bm, Bp, c2m, c2p, Z,
                      sm, sp[1], sp[0], s_mfin, s_pfin);
    x0 = cvt8(Q0, Q1);   // x(t+2)
    x1 = cvt8(Q2, Q3);
    pxl += 2 * F_DIM;
  }
  // ---- tail: steps 510, 511 (x0=x(510), R=raw x(511); 511 writes finals)
  step_cells<false>(arow, g8, j, rowb, x0, x1, mo0, mo1,
                    Bm, Bp, c2m, c2p, Z,
                    sm, sp[0], sp[1], s_mfin, s_pfin);
  x0 = cvt8(R0, R1);
  x1 = cvt8(R2, R3);
  step_cells<true>(arow, g8, j, rowb, x0, x1, mo0, mo1,
                   Bm, Bp, c2m, c2p, Z,
                   sm, sp[1], sp[0], s_mfin, s_pfin);
  __syncthreads();   // finals visible to head threads (full drain, once)

  // ---- heads
  if (tid < NB) {
    const int b = tid;
    float acc = plb[0];
#pragma unroll 1
    for (int k = 0; k < 64; ++k) acc += s_pfin[b][k] * plW[k];
    out[b0 + b] = acc;
  } else if (tid < NB + NB * 8) {
    const int r = tid - NB;
    const int b = r >> 3, e = r & 7;
    float acc = mlb[e];
#pragma unroll 1
    for (int k = 0; k < 64; ++k) acc += s_mfin[b][k] * mlW[e * 64 + k];
    out[(size_t)B + (size_t)(b0 + b) * 8 + e] = acc;
  }
}

extern "C" void kernel_launch(void* const* d_in, const int* in_sizes, int n_in,
                              void* d_out, int out_size, void* d_ws, size_t ws_size,
                              hipStream_t stream) {
  (void)n_in; (void)out_size; (void)d_ws; (void)ws_size;
  const float* x    = (const float*)d_in[0];
  const float* mWih = (const float*)d_in[1];
  const float* mWhh = (const float*)d_in[2];
  const float* mbih = (const float*)d_in[3];
  const float* mbhh = (const float*)d_in[4];
  const float* pWih = (const float*)d_in[5];
  const float* pWhh = (const float*)d_in[6];
  const float* pbih = (const float*)d_in[7];
  const float* pbhh = (const float*)d_in[8];
  const float* plW  = (const float*)d_in[9];
  const float* plb  = (const float*)d_in[10];
  const float* mlW  = (const float*)d_in[11];
  const float* mlb  = (const float*)d_in[12];
  const int B = in_sizes[0] / (T_LEN * F_DIM);
  const int nblk = B / NB;   // 256 blocks -> 1 block/CU, 16 valid rows/MFMA
  mr_rnn_kernel<<<dim3(nblk), dim3(256), 0, stream>>>(
      x, mWih, mWhh, mbih, mbhh, pWih, pWhh, pbih, pbhh,
      plW, plb, mlW, mlb, (float*)d_out, B);
}